// Round 5
// baseline (326.606 us; speedup 1.0000x reference)
//
#include <hip/hip_runtime.h>
#include <hip/hip_cooperative_groups.h>
#include <math.h>

namespace cg = cooperative_groups;

// ---------------- problem constants ----------------
#define NB 16
#define SECL 8
#define WORDL 512
#define SS 4096          // SECL*WORDL
#define HH 256           // H
#define EE 128           // E
#define VV 50000
#define NOOV 32
#define VO 50032         // V+NOOV
#define EOS_ID 3
#define H2 512           // 2H
#define KOUT 768         // 3H
#define NCH 13           // vocab chunks
#define CHSZ 4096

// ---------------- d_out offsets (floats) ----------------
#define OFF_FINAL 0
#define OFF_H    800512
#define OFF_C    804608
#define OFF_CTX  808704
#define OFF_ATTN 816896
#define OFF_COV  882432
#define OFF_FOC  947968
#define OFF_SAD  948096

// ---------------- ws offsets (floats) ----------------
#define WX     0         // x: 16*128
#define WD     2048      // d: 16*512
#define WDF    10240     // dfeat: 16*512
#define WSC    18432     // sc: 16*8 (fallback path)
#define WGI    18560     // gidx: 32 ints
#define WTF    18592     // topk focus: 32
#define WSG    18624     // score_g: 16*1024
#define WPART  35008     // context partials: 16*16*512
#define WPG    166080    // p_gen: 16
#define WPM    166096    // partial max: 208
#define WPS    166304    // partial sum: 208
#define WLG    166512    // logits: 16*50000
#define WSCP   966512    // sec partials: 512 (coop path)

__device__ __forceinline__ float sigm(float x){ return 1.f/(1.f+__expf(-x)); }
__device__ __forceinline__ float tfast(float x){
  float ax = fabsf(x);
  float e  = __expf(-2.f*ax);
  float t  = (1.f-e)/(1.f+e);
  return x < 0.f ? -t : t;
}
__device__ __forceinline__ float dot4(float acc, float4 a, float4 b){
  acc = fmaf(a.x,b.x,acc); acc = fmaf(a.y,b.y,acc);
  acc = fmaf(a.z,b.z,acc); acc = fmaf(a.w,b.w,acc);
  return acc;
}
__device__ __forceinline__ float dot2(float acc, float2 a, float2 b){
  acc = fmaf(a.x,b.x,acc); acc = fmaf(a.y,b.y,acc);
  return acc;
}
__device__ __forceinline__ float mergep(float a, float b, int k, int lane){
  float send = (lane & k) ? a : b;
  float recv = __shfl_xor(send, k);
  return (lane & k) ? b + recv : a + recv;
}
// acc[0..7] -> p where p(lane) = full-wave sum of acc[lane&7]
__device__ __forceinline__ float reduce8(float acc[8], int lane){
  float m0 = mergep(acc[0], acc[1], 1, lane);
  float m1 = mergep(acc[2], acc[3], 1, lane);
  float m2 = mergep(acc[4], acc[5], 1, lane);
  float m3 = mergep(acc[6], acc[7], 1, lane);
  float n0 = mergep(m0, m1, 2, lane);
  float n1 = mergep(m2, m3, 2, lane);
  float p  = mergep(n0, n1, 4, lane);
  p += __shfl_xor(p, 8);
  p += __shfl_xor(p, 16);
  p += __shfl_xor(p, 32);
  return p;
}

// ======== device phase bodies (shared by coop kernel and fallbacks) ========

__device__ __forceinline__ void phase_x(int gw, int lane,
    const int* inp, const float* pc, const float* emb,
    const float* Wc, const float* bc, float* ws){
  int bg = gw & 1, e = gw >> 1;
  float4 z = {0,0,0,0};
  float4 i0[8], i1[8], i2[8];
  #pragma unroll
  for(int j=0;j<8;j++){
    int b = bg*8 + j;
    i0[j] = *(const float4*)(pc + b*H2 + lane*4);
    i1[j] = *(const float4*)(pc + b*H2 + 256 + lane*4);
    i2[j] = (lane < 32) ? *(const float4*)(emb + (size_t)inp[b]*EE + lane*4) : z;
  }
  const float* wr = Wc + (size_t)e*(H2+EE);
  float4 w0 = *(const float4*)(wr + lane*4);
  float4 w1 = *(const float4*)(wr + 256 + lane*4);
  float4 w2 = (lane < 32) ? *(const float4*)(wr + 512 + lane*4) : z;
  float acc[8];
  #pragma unroll
  for(int j=0;j<8;j++){
    float a = dot4(0.f, w0, i0[j]);
    a = dot4(a, w1, i1[j]);
    a = dot4(a, w2, i2[j]);
    acc[j] = a;
  }
  float p = reduce8(acc, lane);
  if(lane < 8) ws[WX + (bg*8+lane)*EE + e] = p + bc[e];
}

__device__ __forceinline__ void phase_gates(int blk, int wv, int lane, int tid,
    const float* h, const float* c, const float* Wih, const float* Whh,
    const float* bih, const float* bhh, const float* ws, float* out,
    float (*g_lds)[8]){
  int j  = blk >> 1;
  int bg = blk & 1;
  float2 xb[8]; float4 hb[8];
  #pragma unroll
  for(int q=0;q<8;q++){
    int b = bg*8 + q;
    xb[q] = *(const float2*)(ws + WX + b*EE + lane*2);
    hb[q] = *(const float4*)(h + b*HH + lane*4);
  }
  int r = wv*HH + j;
  float2 wx = *(const float2*)(Wih + (size_t)r*EE + lane*2);
  float4 wh = *(const float4*)(Whh + (size_t)r*HH + lane*4);
  float acc[8];
  #pragma unroll
  for(int q=0;q<8;q++)
    acc[q] = dot4(dot2(0.f, wx, xb[q]), wh, hb[q]);
  float p = reduce8(acc, lane);
  if(lane < 8) g_lds[wv][lane] = p + bih[r] + bhh[r];
  __syncthreads();
  if(tid < 8){
    int b = bg*8 + tid;
    float g0 = g_lds[0][tid], g1 = g_lds[1][tid];
    float g2 = g_lds[2][tid], g3 = g_lds[3][tid];
    float cn = sigm(g1)*c[b*HH + j] + sigm(g0)*tfast(g2);
    float hn = sigm(g3)*tfast(cn);
    out[OFF_H + b*HH + j] = hn;
    out[OFF_C + b*HH + j] = cn;
  }
}

__device__ __forceinline__ void phase_dd(int gw, int lane,
    const float* Wd, const float* bd, const float* Wdec, const float* bdec,
    const float* out, float* ws){
  int bg = gw & 1, sel = (gw >> 1) & 1, j = gw >> 2;
  float4 d0[8], d1[8];
  #pragma unroll
  for(int q=0;q<8;q++){
    int b = bg*8 + q;
    d0[q] = *(const float4*)(out + OFF_H + b*HH + lane*4);
    d1[q] = *(const float4*)(out + OFF_C + b*HH + lane*4);
  }
  const float* wr = (sel ? Wdec : Wd) + (size_t)j*H2;
  float4 w0 = *(const float4*)(wr + lane*4);
  float4 w1 = *(const float4*)(wr + 256 + lane*4);
  float acc[8];
  #pragma unroll
  for(int q=0;q<8;q++)
    acc[q] = dot4(dot4(0.f, w0, d0[q]), w1, d1[q]);
  float p = reduce8(acc, lane);
  if(lane < 8) ws[(sel ? WDF : WD) + (bg*8+lane)*H2 + j] = p + (sel ? bdec : bd)[j];
}

// focus logic given sc[8] already summed; thread b in [0,16)
__device__ __forceinline__ void focus_body(int b, float sc[SECL],
    const int* inp, const float* smask, const float* focus_in,
    float* ws, float* out){
  float sad[SECL], f[SECL];
  float mx = -1e30f;
  for(int l=0;l<SECL;l++) mx = fmaxf(mx, sc[l]);
  float sum = 0.f;
  for(int l=0;l<SECL;l++){ sad[l] = __expf(sc[l]-mx); sum += sad[l]; }
  float s2 = 0.f;
  for(int l=0;l<SECL;l++){ sad[l] = sad[l]/sum * smask[b*SECL+l]; s2 += sad[l]; }
  for(int l=0;l<SECL;l++){ sad[l] /= s2; out[OFF_SAD + b*SECL + l] = sad[l]; }
  for(int l=0;l<SECL;l++) f[l] = focus_in[b*SECL+l];
  int fi = SECL;
  for(int l=0;l<SECL;l++){ if(f[l] != 0.f){ fi = l; break; } }
  float rem[SECL];
  for(int l=0;l<SECL;l++) rem[l] = (l > fi) ? sad[l] : 0.f;
  float mrb = rem[0]; int mri = 0;
  for(int l=1;l<SECL;l++){ if(rem[l] > mrb){ mrb = rem[l]; mri = l; } }
  float fbm = (fi < SECL) ? sad[fi] : 0.f;
  int cmp = (fbm*2.f > mrb);
  int src = (mrb != 0.f);
  float amb[SECL];
  for(int l=0;l<SECL;l++) amb[l] = (src && l > mri) ? sad[l] : 0.f;
  float am = amb[0]; int ai = 0;
  for(int l=1;l<SECL;l++){ if(amb[l] > am){ am = amb[l]; ai = l; } }
  float fu[SECL]; float fs = 0.f;
  for(int l=0;l<SECL;l++){
    float mrm = (src && l == mri) ? 1.f : 0.f;
    float mam = ((am != 0.f) && l == ai) ? 1.f : 0.f;
    float cf = ((l==fi) ? sad[l] : 0.f) + sad[l]*mrm;
    float cr = sad[l]*(mrm + mam);
    fu[l] = cmp ? cf : cr;
    fs += fu[l];
  }
  float eos = (inp[b] == EOS_ID) ? 1.f : 0.f;
  float fo[SECL];
  for(int l=0;l<SECL;l++){
    fo[l] = eos*(fu[l]/fs) + (1.f-eos)*f[l];
    out[OFF_FOC + b*SECL + l] = fo[l];
  }
  float v1 = fo[0]; int i1 = 0;
  for(int l=1;l<SECL;l++){ if(fo[l] > v1){ v1 = fo[l]; i1 = l; } }
  float v2 = -1e30f; int i2 = 0;
  for(int l=0;l<SECL;l++){ if(l != i1 && fo[l] > v2){ v2 = fo[l]; i2 = l; } }
  ((int*)ws)[WGI + b*2]     = i1;
  ((int*)ws)[WGI + b*2 + 1] = i2;
  ws[WTF + b*2]     = v1;
  ws[WTF + b*2 + 1] = v2;
}

// ======== fused cooperative front kernel: x -> LSTM -> d/dfeat -> sec -> focus
__global__ void __launch_bounds__(256)
k_front2(const int* __restrict__ inp, const float* __restrict__ pc,
         const float* __restrict__ emb, const float* __restrict__ Wc,
         const float* __restrict__ bc,
         const float* __restrict__ h, const float* __restrict__ c,
         const float* __restrict__ Wih, const float* __restrict__ Whh,
         const float* __restrict__ bih, const float* __restrict__ bhh,
         const float* __restrict__ Wd, const float* __restrict__ bd,
         const float* __restrict__ Wdec, const float* __restrict__ bdec,
         const float* __restrict__ eso, const float* __restrict__ Wf,
         const float* __restrict__ vsec,
         const float* __restrict__ smask, const float* __restrict__ foc,
         float* __restrict__ ws, float* __restrict__ out){
  cg::grid_group grid = cg::this_grid();
  __shared__ float g_lds[4][8];
  __shared__ float red[4];
  int tid  = threadIdx.x;
  int lane = tid & 63;
  int wv   = tid >> 6;
  int blk  = blockIdx.x;     // 512 blocks

  // P1: x (blocks 0..63)
  if(blk < 64) phase_x(blk*4 + wv, lane, inp, pc, emb, Wc, bc, ws);
  grid.sync();
  // P2: gates + LSTM nonlinearity (all 512 blocks)
  phase_gates(blk, wv, lane, tid, h, c, Wih, Whh, bih, bhh, ws, out, g_lds);
  grid.sync();
  // P3: d / dfeat (512 blocks x 4 waves = 2048 rows)
  phase_dd(blk*4 + wv, lane, Wd, bd, Wdec, bdec, out, ws);
  grid.sync();
  // P4: section-score partials: blk = bl*4 + part, 4 t-iters each
  {
    int bl = blk >> 2, part = blk & 3;
    int b = bl >> 3;
    const float* ep = eso + (size_t)bl*H2;
    float4 es0 = *(const float4*)(ep + lane*4);
    float4 es1 = *(const float4*)(ep + 256 + lane*4);
    const float* dp = ws + WD + b*H2;
    float local = 0.f;
    for(int tt=0;tt<4;tt++){
      int t = part*4 + tt;
      int j0 = wv*8 + t*32;
      float acc[8];
      #pragma unroll
      for(int jj=0;jj<8;jj++){
        const float* wr = Wf + (size_t)(j0+jj)*H2;
        float4 w0 = *(const float4*)(wr + lane*4);
        float4 w1 = *(const float4*)(wr + 256 + lane*4);
        acc[jj] = dot4(dot4(0.f, w0, es0), w1, es1);
      }
      float p = reduce8(acc, lane);
      if(lane < 8){
        int j = j0 + lane;
        local += tfast(p + dp[j]) * vsec[j];
      }
    }
    local += __shfl_xor(local, 1);
    local += __shfl_xor(local, 2);
    local += __shfl_xor(local, 4);
    if(lane == 0) red[wv] = local;
    __syncthreads();
    if(tid == 0) ws[WSCP + blk] = red[0]+red[1]+red[2]+red[3];
  }
  grid.sync();
  // P5: sad softmax + focus update + top-2 (block 0)
  if(blk == 0 && tid < NB){
    int b = tid;
    float sc[SECL];
    for(int l=0;l<SECL;l++){
      int bl = b*SECL + l;
      sc[l] = ws[WSCP + bl*4] + ws[WSCP + bl*4+1]
            + ws[WSCP + bl*4+2] + ws[WSCP + bl*4+3];
    }
    focus_body(b, sc, inp, smask, foc, ws, out);
  }
}

// ======== fallback standalone front kernels (used if coop launch fails) ====
__global__ void __launch_bounds__(256)
k_x(const int* __restrict__ inp, const float* __restrict__ pc,
    const float* __restrict__ emb, const float* __restrict__ Wc,
    const float* __restrict__ bc, float* __restrict__ ws){
  phase_x(blockIdx.x*4 + (threadIdx.x>>6), threadIdx.x & 63, inp, pc, emb, Wc, bc, ws);
}
__global__ void __launch_bounds__(256)
k_gates(const float* __restrict__ h, const float* __restrict__ c,
        const float* __restrict__ Wih, const float* __restrict__ Whh,
        const float* __restrict__ bih, const float* __restrict__ bhh,
        const float* __restrict__ ws, float* __restrict__ out){
  __shared__ float g_lds[4][8];
  phase_gates(blockIdx.x, threadIdx.x>>6, threadIdx.x&63, threadIdx.x,
              h, c, Wih, Whh, bih, bhh, ws, out, g_lds);
}
__global__ void __launch_bounds__(256)
k_dd(const float* __restrict__ Wd, const float* __restrict__ bd,
     const float* __restrict__ Wdec, const float* __restrict__ bdec,
     const float* __restrict__ out, float* __restrict__ ws){
  phase_dd(blockIdx.x*4 + (threadIdx.x>>6), threadIdx.x&63, Wd, bd, Wdec, bdec, out, ws);
}
__global__ void __launch_bounds__(256)
k_sec(const float* __restrict__ eso, const float* __restrict__ Wf,
      const float* __restrict__ vsec, float* __restrict__ ws){
  __shared__ float red[4];
  int lane = threadIdx.x & 63;
  int wv   = threadIdx.x >> 6;
  int bl = blockIdx.x; int b = bl >> 3;
  const float* ep = eso + (size_t)bl*H2;
  float4 es0 = *(const float4*)(ep + lane*4);
  float4 es1 = *(const float4*)(ep + 256 + lane*4);
  const float* dp = ws + WD + b*H2;
  float local = 0.f;
  for(int t=0;t<16;t++){
    int j0 = wv*8 + t*32;
    float acc[8];
    #pragma unroll
    for(int jj=0;jj<8;jj++){
      const float* wr = Wf + (size_t)(j0+jj)*H2;
      float4 w0 = *(const float4*)(wr + lane*4);
      float4 w1 = *(const float4*)(wr + 256 + lane*4);
      acc[jj] = dot4(dot4(0.f, w0, es0), w1, es1);
    }
    float p = reduce8(acc, lane);
    if(lane < 8){
      int j = j0 + lane;
      local += tfast(p + dp[j]) * vsec[j];
    }
  }
  local += __shfl_xor(local, 1);
  local += __shfl_xor(local, 2);
  local += __shfl_xor(local, 4);
  if(lane == 0) red[wv] = local;
  __syncthreads();
  if(threadIdx.x == 0) ws[WSC + bl] = red[0]+red[1]+red[2]+red[3];
}
__global__ void k_focus(const int* __restrict__ inp, const float* __restrict__ smask,
                        const float* __restrict__ focus_in, float* __restrict__ ws,
                        float* __restrict__ out){
  int b = threadIdx.x;
  if(b >= NB) return;
  float sc[SECL];
  for(int l=0;l<SECL;l++) sc[l] = ws[WSC + b*SECL + l];
  focus_body(b, sc, inp, smask, focus_in, ws, out);
}

// ======== attention / output kernels ========

__global__ void k_score(const float* __restrict__ ef, const float* __restrict__ cov,
                        const float* __restrict__ wcov, const float* __restrict__ vatt,
                        float* __restrict__ ws){
  int lane = threadIdx.x & 63;
  int o = blockIdx.x*4 + (threadIdx.x >> 6); // < 16384
  int b = o >> 10, fidx = (o >> 9) & 1, w = o & 511;
  int g = ((const int*)ws)[WGI + b*2 + fidx];
  int s = g*WORDL + w;
  const float* e  = ef + ((size_t)(b*SS + s))*H2;
  const float* df = ws + WDF + b*H2;
  float cv = cov[b*SS + s];
  int j = lane*4;
  float local = 0.f;
  #pragma unroll
  for(int half=0; half<2; half++){
    int jj = j + half*256;
    float4 a  = *(const float4*)(e+jj);
    float4 d4 = *(const float4*)(df+jj);
    float4 wc = *(const float4*)(wcov+jj);
    float4 va = *(const float4*)(vatt+jj);
    local += tfast(a.x + d4.x + cv*wc.x)*va.x;
    local += tfast(a.y + d4.y + cv*wc.y)*va.y;
    local += tfast(a.z + d4.z + cv*wc.z)*va.z;
    local += tfast(a.w + d4.w + cv*wc.w)*va.w;
  }
  for(int off=32; off>0; off>>=1) local += __shfl_xor(local, off);
  if(lane == 0) ws[WSG + o] = local;
}

__global__ void k_af(const float* __restrict__ emask, const float* __restrict__ cov,
                     float* __restrict__ ws, float* __restrict__ out){
  __shared__ float es[1024];
  __shared__ float red[256];
  int b = blockIdx.x, tid = threadIdx.x;
  int g0 = ((int*)ws)[WGI+b*2], g1 = ((int*)ws)[WGI+b*2+1];
  float tf0 = ws[WTF+b*2], tf1 = ws[WTF+b*2+1];
  float lm = -1e30f;
  for(int i=tid;i<1024;i+=256) lm = fmaxf(lm, ws[WSG + b*1024 + i]);
  red[tid] = lm; __syncthreads();
  for(int off=128; off; off>>=1){
    if(tid < off) red[tid] = fmaxf(red[tid], red[tid+off]);
    __syncthreads();
  }
  float mx = red[0]; __syncthreads();
  float ls0 = 0.f, ls1 = 0.f;
  for(int i=tid;i<1024;i+=256){
    int fidx = i >> 9, w = i & 511;
    int g = fidx ? g1 : g0;
    float m = emask[b*SS + g*WORDL + w];
    float ev = __expf(ws[WSG + b*1024 + i] - mx)*m;
    es[i] = ev;
    if(fidx) ls1 += ev; else ls0 += ev;
  }
  red[tid] = ls0; __syncthreads();
  for(int off=128; off; off>>=1){ if(tid<off) red[tid]+=red[tid+off]; __syncthreads(); }
  float sum0 = red[0]; __syncthreads();
  red[tid] = ls1; __syncthreads();
  for(int off=128; off; off>>=1){ if(tid<off) red[tid]+=red[tid+off]; __syncthreads(); }
  float sum1 = red[0]; __syncthreads();
  float inv = 1.f/(tf0*sum0 + tf1*sum1);
  for(int s=tid;s<SS;s+=256){
    int sec = s >> 9, w = s & 511;
    float a = 0.f;
    if(sec == g0)      a = tf0*es[w]*inv;
    else if(sec == g1) a = tf1*es[512+w]*inv;
    out[OFF_ATTN + b*SS + s] = a;
    out[OFF_COV  + b*SS + s] = cov[b*SS+s] + a;
  }
}

__global__ void k_ctxp(const float* __restrict__ eo, const float* __restrict__ out,
                       float* __restrict__ ws){
  int blk = blockIdx.x; int b = blk >> 4, ch = blk & 15;
  int d = threadIdx.x;
  int g0 = ((const int*)ws)[WGI + b*2];
  int g1 = ((const int*)ws)[WGI + b*2 + 1];
  float a0 = 0.f, a1 = 0.f;
  #pragma unroll 4
  for(int p = ch*64; p < ch*64 + 64; p++){
    int s = ((p >> 9) ? g1 : g0)*WORDL + (p & 511);
    float a = out[OFF_ATTN + b*SS + s];
    const float* ep = eo + ((size_t)(b*SS + s))*H2;
    a0 = fmaf(a, ep[d],       a0);
    a1 = fmaf(a, ep[d+256],   a1);
  }
  ws[WPART + (size_t)blk*H2 + d]       = a0;
  ws[WPART + (size_t)blk*H2 + d + 256] = a1;
}

__global__ void k_ctx(const float* __restrict__ Wp, const float* __restrict__ bp,
                      float* __restrict__ ws, float* __restrict__ out){
  __shared__ float red[256];
  int b = blockIdx.x, tid = threadIdx.x;
  float c0 = 0.f, c1 = 0.f;
  for(int ch=0; ch<16; ch++){
    c0 += ws[WPART + (size_t)(b*16+ch)*H2 + tid];
    c1 += ws[WPART + (size_t)(b*16+ch)*H2 + tid + 256];
  }
  out[OFF_CTX + b*H2 + tid]       = c0;
  out[OFF_CTX + b*H2 + tid + 256] = c1;
  float hn = out[OFF_H + b*HH + tid];
  float cn = out[OFF_C + b*HH + tid];
  float pv = c0*Wp[tid] + c1*Wp[tid+256] + hn*Wp[512+tid] + cn*Wp[768+tid];
  if(tid < EE) pv = fmaf(ws[WX + b*EE + tid], Wp[1024+tid], pv);
  red[tid] = pv; __syncthreads();
  for(int off=128; off; off>>=1){ if(tid<off) red[tid]+=red[tid+off]; __syncthreads(); }
  if(tid == 0) ws[WPG + b] = sigm(red[0] + bp[0]);
}

// logits: 8 consecutive rows per wave, 2-deep register prefetch.
// grid 3125 x (2 b-octets x 2 row-halves); 3125*16 = 50000 exactly.
__global__ void __launch_bounds__(256,3)
k_logits(const float* __restrict__ Wout, const float* __restrict__ bout,
         const float* __restrict__ out, float* __restrict__ ws){
  int lane = threadIdx.x & 63;
  int wv   = threadIdx.x >> 6;
  int bg   = wv & 1;
  int rh   = wv >> 1;
  float4 hb0[8], hb1[8], hb2[8];
  #pragma unroll
  for(int j=0;j<8;j++){
    int b = bg*8 + j;
    hb0[j] = *(const float4*)(out + OFF_H   + b*HH + lane*4);
    hb1[j] = *(const float4*)(out + OFF_CTX + b*H2 + lane*4);
    hb2[j] = *(const float4*)(out + OFF_CTX + b*H2 + 256 + lane*4);
  }
  int v0 = blockIdx.x*16 + rh*8;
  const float* w0p = Wout + (size_t)v0*KOUT + lane*4;
  float4 A0 = *(const float4*)(w0p);
  float4 A1 = *(const float4*)(w0p+256);
  float4 A2 = *(const float4*)(w0p+512);
  const float* w1p = w0p + KOUT;
  float4 B0 = *(const float4*)(w1p);
  float4 B1 = *(const float4*)(w1p+256);
  float4 B2 = *(const float4*)(w1p+512);
  #pragma unroll
  for(int r=0;r<8;r++){
    float4 C0=A0, C1=A1, C2=A2;
    if(r < 6){
      const float* np = w0p + (size_t)(r+2)*KOUT;
      C0 = *(const float4*)(np);
      C1 = *(const float4*)(np+256);
      C2 = *(const float4*)(np+512);
    }
    float acc[8];
    #pragma unroll
    for(int j=0;j<8;j++){
      float a = dot4(0.f, A0, hb0[j]);
      a = dot4(a, A1, hb1[j]);
      a = dot4(a, A2, hb2[j]);
      acc[j] = a;
    }
    float p = reduce8(acc, lane);
    int v = v0 + r;
    if(lane < 8) ws[WLG + (size_t)(bg*8+lane)*VV + v] = p + bout[v];
    A0=B0; A1=B1; A2=B2;
    B0=C0; B1=C1; B2=C2;
  }
}

__global__ void k_vms(float* __restrict__ ws){
  __shared__ float rm[256], rs[256];
  int blk = blockIdx.x; int b = blk/NCH, ch = blk%NCH;
  int tid = threadIdx.x;
  int v0 = ch*CHSZ; int v1 = v0+CHSZ; if(v1 > VV) v1 = VV;
  float mt = -1e30f, st = 0.f;
  for(int v=v0+tid; v<v1; v+=256){
    float x = ws[WLG + (size_t)b*VV + v];
    if(x > mt){ st = st*__expf(mt - x) + 1.f; mt = x; }
    else       st += __expf(x - mt);
  }
  rm[tid] = mt; rs[tid] = st; __syncthreads();
  for(int off=128; off; off>>=1){
    if(tid < off){
      float ma = rm[tid], mb = rm[tid+off];
      float M = fmaxf(ma, mb);
      rs[tid] = rs[tid]*__expf(ma-M) + rs[tid+off]*__expf(mb-M);
      rm[tid] = M;
    }
    __syncthreads();
  }
  if(tid == 0){ ws[WPM + blk] = rm[0]; ws[WPS + blk] = rs[0]; }
}

__global__ void k_final(const float* __restrict__ zoov, float* __restrict__ ws,
                        float* __restrict__ out){
  int blk = blockIdx.x; int b = blk/NCH, ch = blk%NCH;
  float mx = -1e30f, sm = 0.f;
  for(int i=0;i<NCH;i++){ mx = fmaxf(mx, ws[WPM + b*NCH + i]); }
  for(int i=0;i<NCH;i++){ sm += ws[WPS + b*NCH + i]*__expf(ws[WPM + b*NCH + i] - mx); }
  float scale = ws[WPG + b] / sm;
  int v0 = ch*CHSZ; int v1 = v0+CHSZ; if(v1 > VO) v1 = VO;
  for(int v=v0+threadIdx.x; v<v1; v+=256){
    float r;
    if(v < VV) r = scale*__expf(ws[WLG + (size_t)b*VV + v] - mx);
    else       r = zoov[b*NOOV + v - VV];
    out[OFF_FINAL + (size_t)b*VO + v] = r;
  }
}

__global__ void k_scatter(const int* __restrict__ oov, const float* __restrict__ ws,
                          float* __restrict__ out){
  int blk = blockIdx.x; int b = blk >> 4;
  int s = (blk & 15)*256 + threadIdx.x;
  float a = out[OFF_ATTN + b*SS + s];
  if(a != 0.f){
    float w = (1.f - ws[WPG + b])*a;
    atomicAdd(out + OFF_FINAL + (size_t)b*VO + oov[b*SS + s], w);
  }
}

extern "C" void kernel_launch(void* const* d_in, const int* in_sizes, int n_in,
                              void* d_out, int out_size, void* d_ws, size_t ws_size,
                              hipStream_t stream){
  const int*   inp   = (const int*)  d_in[0];
  const float* h     = (const float*)d_in[1];
  const float* c     = (const float*)d_in[2];
  const float* eo    = (const float*)d_in[3];
  const float* efeat = (const float*)d_in[4];
  const float* eso   = (const float*)d_in[5];
  const float* emask = (const float*)d_in[6];
  const float* smask = (const float*)d_in[7];
  const float* pctx  = (const float*)d_in[8];
  const float* zoov  = (const float*)d_in[9];
  const int*   oov   = (const int*)  d_in[10];
  const float* cov   = (const float*)d_in[11];
  const float* foc   = (const float*)d_in[12];
  const float* emb   = (const float*)d_in[13];
  const float* Wc    = (const float*)d_in[14];
  const float* bc    = (const float*)d_in[15];
  const float* Wih   = (const float*)d_in[16];
  const float* Whh   = (const float*)d_in[17];
  const float* bih   = (const float*)d_in[18];
  const float* bhh   = (const float*)d_in[19];
  const float* Wd    = (const float*)d_in[20];
  const float* bd    = (const float*)d_in[21];
  const float* Wf    = (const float*)d_in[22];
  const float* vsec  = (const float*)d_in[23];
  const float* Wdec  = (const float*)d_in[24];
  const float* bdec  = (const float*)d_in[25];
  const float* wcov  = (const float*)d_in[26];
  const float* vatt  = (const float*)d_in[27];
  const float* Wp    = (const float*)d_in[28];
  const float* bp    = (const float*)d_in[29];
  const float* Wout  = (const float*)d_in[30];
  const float* bout  = (const float*)d_in[31];
  float* out = (float*)d_out;
  float* ws  = (float*)d_ws;

  void* fargs[] = {
    (void*)&inp, (void*)&pctx, (void*)&emb, (void*)&Wc, (void*)&bc,
    (void*)&h, (void*)&c, (void*)&Wih, (void*)&Whh, (void*)&bih, (void*)&bhh,
    (void*)&Wd, (void*)&bd, (void*)&Wdec, (void*)&bdec,
    (void*)&eso, (void*)&Wf, (void*)&vsec, (void*)&smask, (void*)&foc,
    (void*)&ws, (void*)&out
  };
  hipError_t ce = hipLaunchCooperativeKernel((void*)k_front2, dim3(512), dim3(256),
                                             fargs, 0, stream);
  if(ce != hipSuccess){
    k_x     <<<64,  256, 0, stream>>>(inp, pctx, emb, Wc, bc, ws);
    k_gates <<<512, 256, 0, stream>>>(h, c, Wih, Whh, bih, bhh, ws, out);
    k_dd    <<<512, 256, 0, stream>>>(Wd, bd, Wdec, bdec, out, ws);
    k_sec   <<<128, 256, 0, stream>>>(eso, Wf, vsec, ws);
    k_focus <<<1,    64, 0, stream>>>(inp, smask, foc, ws, out);
  }
  k_score  <<<4096, 256, 0, stream>>>(efeat, cov, wcov, vatt, ws);
  k_af     <<<16,   256, 0, stream>>>(emask, cov, ws, out);
  k_ctxp   <<<256,  256, 0, stream>>>(eo, out, ws);
  k_ctx    <<<16,   256, 0, stream>>>(Wp, bp, ws, out);
  k_logits <<<3125, 256, 0, stream>>>(Wout, bout, out, ws);
  k_vms    <<<208,  256, 0, stream>>>(ws);
  k_final  <<<208,  256, 0, stream>>>(zoov, ws, out);
  k_scatter<<<256,  256, 0, stream>>>(oov, ws, out);
}

// Round 6
// 155.430 us; speedup vs baseline: 2.1013x; 2.1013x over previous
//
#include <hip/hip_runtime.h>
#include <math.h>

// ---------------- problem constants ----------------
#define NB 16
#define SECL 8
#define WORDL 512
#define SS 4096          // SECL*WORDL
#define HH 256           // H
#define EE 128           // E
#define VV 50000
#define NOOV 32
#define VO 50032         // V+NOOV
#define EOS_ID 3
#define H2 512           // 2H
#define KOUT 768         // 3H
#define NCH 13           // vocab chunks
#define CHSZ 4096

// ---------------- d_out offsets (floats) ----------------
#define OFF_FINAL 0
#define OFF_H    800512
#define OFF_C    804608
#define OFF_CTX  808704
#define OFF_ATTN 816896
#define OFF_COV  882432
#define OFF_FOC  947968
#define OFF_SAD  948096

// ---------------- ws offsets (floats) ----------------
#define WX     0         // x: 16*128
#define WD     2048      // d: 16*512
#define WDF    10240     // dfeat: 16*512
#define WSC    18432     // sc: 16*8
#define WGI    18560     // gidx: 32 ints
#define WTF    18592     // topk focus: 32
#define WSG    18624     // score_g: 16*1024
#define WPART  35008     // context partials: 16*16*512
#define WPG    166080    // p_gen: 16
#define WPM    166096    // partial max: 208
#define WPS    166304    // partial sum: 208
#define WLG    166512    // logits: 16*50000

__device__ __forceinline__ float sigm(float x){ return 1.f/(1.f+__expf(-x)); }
__device__ __forceinline__ float tfast(float x){
  float ax = fabsf(x);
  float e  = __expf(-2.f*ax);
  float t  = (1.f-e)/(1.f+e);
  return x < 0.f ? -t : t;
}
__device__ __forceinline__ float dot4(float acc, float4 a, float4 b){
  acc = fmaf(a.x,b.x,acc); acc = fmaf(a.y,b.y,acc);
  acc = fmaf(a.z,b.z,acc); acc = fmaf(a.w,b.w,acc);
  return acc;
}
__device__ __forceinline__ float dot2(float acc, float2 a, float2 b){
  acc = fmaf(a.x,b.x,acc); acc = fmaf(a.y,b.y,acc);
  return acc;
}
__device__ __forceinline__ float mergep(float a, float b, int k, int lane){
  float send = (lane & k) ? a : b;
  float recv = __shfl_xor(send, k);
  return (lane & k) ? b + recv : a + recv;
}
// acc[0..7] -> p where p(lane) = full-wave sum of acc[lane&7]
__device__ __forceinline__ float reduce8(float acc[8], int lane){
  float m0 = mergep(acc[0], acc[1], 1, lane);
  float m1 = mergep(acc[2], acc[3], 1, lane);
  float m2 = mergep(acc[4], acc[5], 1, lane);
  float m3 = mergep(acc[6], acc[7], 1, lane);
  float n0 = mergep(m0, m1, 2, lane);
  float n1 = mergep(m2, m3, 2, lane);
  float p  = mergep(n0, n1, 4, lane);
  p += __shfl_xor(p, 8);
  p += __shfl_xor(p, 16);
  p += __shfl_xor(p, 32);
  return p;
}

// ======== front kernels (R4-proven wave-coalesced matvec skeleton) ========

__global__ void __launch_bounds__(256)
k_x(const int* __restrict__ inp, const float* __restrict__ pc,
    const float* __restrict__ emb, const float* __restrict__ Wc,
    const float* __restrict__ bc, float* __restrict__ ws){
  int lane = threadIdx.x & 63;
  int gw = blockIdx.x*4 + (threadIdx.x >> 6);  // 0..255
  int bg = gw & 1, e = gw >> 1;
  float4 z = {0,0,0,0};
  float4 i0[8], i1[8], i2[8];
  #pragma unroll
  for(int j=0;j<8;j++){
    int b = bg*8 + j;
    i0[j] = *(const float4*)(pc + b*H2 + lane*4);
    i1[j] = *(const float4*)(pc + b*H2 + 256 + lane*4);
    i2[j] = (lane < 32) ? *(const float4*)(emb + (size_t)inp[b]*EE + lane*4) : z;
  }
  const float* wr = Wc + (size_t)e*(H2+EE);
  float4 w0 = *(const float4*)(wr + lane*4);
  float4 w1 = *(const float4*)(wr + 256 + lane*4);
  float4 w2 = (lane < 32) ? *(const float4*)(wr + 512 + lane*4) : z;
  float acc[8];
  #pragma unroll
  for(int j=0;j<8;j++){
    float a = dot4(0.f, w0, i0[j]);
    a = dot4(a, w1, i1[j]);
    a = dot4(a, w2, i2[j]);
    acc[j] = a;
  }
  float p = reduce8(acc, lane);
  if(lane < 8) ws[WX + (bg*8+lane)*EE + e] = p + bc[e];
}

__global__ void __launch_bounds__(256)
k_gates(const float* __restrict__ h, const float* __restrict__ c,
        const float* __restrict__ Wih, const float* __restrict__ Whh,
        const float* __restrict__ bih, const float* __restrict__ bhh,
        const float* __restrict__ ws, float* __restrict__ out){
  __shared__ float g_lds[4][8];
  int lane = threadIdx.x & 63;
  int wv   = threadIdx.x >> 6;
  int j  = blockIdx.x >> 1;
  int bg = blockIdx.x & 1;
  float2 xb[8]; float4 hb[8];
  #pragma unroll
  for(int q=0;q<8;q++){
    int b = bg*8 + q;
    xb[q] = *(const float2*)(ws + WX + b*EE + lane*2);
    hb[q] = *(const float4*)(h + b*HH + lane*4);
  }
  int r = wv*HH + j;
  float2 wx = *(const float2*)(Wih + (size_t)r*EE + lane*2);
  float4 wh = *(const float4*)(Whh + (size_t)r*HH + lane*4);
  float acc[8];
  #pragma unroll
  for(int q=0;q<8;q++)
    acc[q] = dot4(dot2(0.f, wx, xb[q]), wh, hb[q]);
  float p = reduce8(acc, lane);
  if(lane < 8) g_lds[wv][lane] = p + bih[r] + bhh[r];
  __syncthreads();
  if(threadIdx.x < 8){
    int b = bg*8 + threadIdx.x;
    float g0 = g_lds[0][threadIdx.x], g1 = g_lds[1][threadIdx.x];
    float g2 = g_lds[2][threadIdx.x], g3 = g_lds[3][threadIdx.x];
    float cn = sigm(g1)*c[b*HH + j] + sigm(g0)*tfast(g2);
    float hn = sigm(g3)*tfast(cn);
    out[OFF_H + b*HH + j] = hn;
    out[OFF_C + b*HH + j] = cn;
  }
}

__global__ void __launch_bounds__(256)
k_dd(const float* __restrict__ Wd, const float* __restrict__ bd,
     const float* __restrict__ Wdec, const float* __restrict__ bdec,
     const float* __restrict__ out, float* __restrict__ ws){
  int lane = threadIdx.x & 63;
  int gw = blockIdx.x*4 + (threadIdx.x >> 6);  // 0..2047
  int bg = gw & 1, sel = (gw >> 1) & 1, j = gw >> 2;
  float4 d0[8], d1[8];
  #pragma unroll
  for(int q=0;q<8;q++){
    int b = bg*8 + q;
    d0[q] = *(const float4*)(out + OFF_H + b*HH + lane*4);
    d1[q] = *(const float4*)(out + OFF_C + b*HH + lane*4);
  }
  const float* wr = (sel ? Wdec : Wd) + (size_t)j*H2;
  float4 w0 = *(const float4*)(wr + lane*4);
  float4 w1 = *(const float4*)(wr + 256 + lane*4);
  float acc[8];
  #pragma unroll
  for(int q=0;q<8;q++)
    acc[q] = dot4(dot4(0.f, w0, d0[q]), w1, d1[q]);
  float p = reduce8(acc, lane);
  if(lane < 8) ws[(sel ? WDF : WD) + (bg*8+lane)*H2 + j] = p + (sel ? bdec : bd)[j];
}

__global__ void __launch_bounds__(256)
k_sec(const float* __restrict__ eso, const float* __restrict__ Wf,
      const float* __restrict__ vsec, float* __restrict__ ws){
  __shared__ float red[4];
  int lane = threadIdx.x & 63;
  int wv   = threadIdx.x >> 6;
  int bl = blockIdx.x; int b = bl >> 3;
  const float* ep = eso + (size_t)bl*H2;
  float4 es0 = *(const float4*)(ep + lane*4);
  float4 es1 = *(const float4*)(ep + 256 + lane*4);
  const float* dp = ws + WD + b*H2;
  float local = 0.f;
  for(int t=0;t<16;t++){
    int j0 = wv*8 + t*32;
    float acc[8];
    #pragma unroll
    for(int jj=0;jj<8;jj++){
      const float* wr = Wf + (size_t)(j0+jj)*H2;
      float4 w0 = *(const float4*)(wr + lane*4);
      float4 w1 = *(const float4*)(wr + 256 + lane*4);
      acc[jj] = dot4(dot4(0.f, w0, es0), w1, es1);
    }
    float p = reduce8(acc, lane);
    if(lane < 8){
      int j = j0 + lane;
      local += tfast(p + dp[j]) * vsec[j];
    }
  }
  local += __shfl_xor(local, 1);
  local += __shfl_xor(local, 2);
  local += __shfl_xor(local, 4);
  if(lane == 0) red[wv] = local;
  __syncthreads();
  if(threadIdx.x == 0) ws[WSC + bl] = red[0]+red[1]+red[2]+red[3];
}

__global__ void k_focus(const int* __restrict__ inp, const float* __restrict__ smask,
                        const float* __restrict__ focus_in, float* __restrict__ ws,
                        float* __restrict__ out){
  int b = threadIdx.x;
  if(b >= NB) return;
  float sc[SECL], sad[SECL], f[SECL];
  float mx = -1e30f;
  for(int l=0;l<SECL;l++){ sc[l] = ws[WSC + b*SECL + l]; mx = fmaxf(mx, sc[l]); }
  float sum = 0.f;
  for(int l=0;l<SECL;l++){ sad[l] = __expf(sc[l]-mx); sum += sad[l]; }
  float s2 = 0.f;
  for(int l=0;l<SECL;l++){ sad[l] = sad[l]/sum * smask[b*SECL+l]; s2 += sad[l]; }
  for(int l=0;l<SECL;l++){ sad[l] /= s2; out[OFF_SAD + b*SECL + l] = sad[l]; }
  for(int l=0;l<SECL;l++) f[l] = focus_in[b*SECL+l];
  int fi = SECL;
  for(int l=0;l<SECL;l++){ if(f[l] != 0.f){ fi = l; break; } }
  float rem[SECL];
  for(int l=0;l<SECL;l++) rem[l] = (l > fi) ? sad[l] : 0.f;
  float mrb = rem[0]; int mri = 0;
  for(int l=1;l<SECL;l++){ if(rem[l] > mrb){ mrb = rem[l]; mri = l; } }
  float fbm = (fi < SECL) ? sad[fi] : 0.f;
  int cmp = (fbm*2.f > mrb);
  int src = (mrb != 0.f);
  float amb[SECL];
  for(int l=0;l<SECL;l++) amb[l] = (src && l > mri) ? sad[l] : 0.f;
  float am = amb[0]; int ai = 0;
  for(int l=1;l<SECL;l++){ if(amb[l] > am){ am = amb[l]; ai = l; } }
  float fu[SECL]; float fs = 0.f;
  for(int l=0;l<SECL;l++){
    float mrm = (src && l == mri) ? 1.f : 0.f;
    float mam = ((am != 0.f) && l == ai) ? 1.f : 0.f;
    float cf = ((l==fi) ? sad[l] : 0.f) + sad[l]*mrm;
    float cr = sad[l]*(mrm + mam);
    fu[l] = cmp ? cf : cr;
    fs += fu[l];
  }
  float eos = (inp[b] == EOS_ID) ? 1.f : 0.f;
  float fo[SECL];
  for(int l=0;l<SECL;l++){
    fo[l] = eos*(fu[l]/fs) + (1.f-eos)*f[l];
    out[OFF_FOC + b*SECL + l] = fo[l];
  }
  float v1 = fo[0]; int i1 = 0;
  for(int l=1;l<SECL;l++){ if(fo[l] > v1){ v1 = fo[l]; i1 = l; } }
  float v2 = -1e30f; int i2 = 0;
  for(int l=0;l<SECL;l++){ if(l != i1 && fo[l] > v2){ v2 = fo[l]; i2 = l; } }
  ((int*)ws)[WGI + b*2]     = i1;
  ((int*)ws)[WGI + b*2 + 1] = i2;
  ws[WTF + b*2]     = v1;
  ws[WTF + b*2 + 1] = v2;
}

// ======== attention kernels ========

__global__ void k_score(const float* __restrict__ ef, const float* __restrict__ cov,
                        const float* __restrict__ wcov, const float* __restrict__ vatt,
                        float* __restrict__ ws){
  int lane = threadIdx.x & 63;
  int o = blockIdx.x*4 + (threadIdx.x >> 6); // < 16384
  int b = o >> 10, fidx = (o >> 9) & 1, w = o & 511;
  int g = ((const int*)ws)[WGI + b*2 + fidx];
  int s = g*WORDL + w;
  const float* e  = ef + ((size_t)(b*SS + s))*H2;
  const float* df = ws + WDF + b*H2;
  float cv = cov[b*SS + s];
  int j = lane*4;
  float local = 0.f;
  #pragma unroll
  for(int half=0; half<2; half++){
    int jj = j + half*256;
    float4 a  = *(const float4*)(e+jj);
    float4 d4 = *(const float4*)(df+jj);
    float4 wc = *(const float4*)(wcov+jj);
    float4 va = *(const float4*)(vatt+jj);
    local += tfast(a.x + d4.x + cv*wc.x)*va.x;
    local += tfast(a.y + d4.y + cv*wc.y)*va.y;
    local += tfast(a.z + d4.z + cv*wc.z)*va.z;
    local += tfast(a.w + d4.w + cv*wc.w)*va.w;
  }
  for(int off=32; off>0; off>>=1) local += __shfl_xor(local, off);
  if(lane == 0) ws[WSG + o] = local;
}

__global__ void k_af(const float* __restrict__ emask, const float* __restrict__ cov,
                     float* __restrict__ ws, float* __restrict__ out){
  __shared__ float es[1024];
  __shared__ float red[256];
  int b = blockIdx.x, tid = threadIdx.x;
  int g0 = ((int*)ws)[WGI+b*2], g1 = ((int*)ws)[WGI+b*2+1];
  float tf0 = ws[WTF+b*2], tf1 = ws[WTF+b*2+1];
  float lm = -1e30f;
  for(int i=tid;i<1024;i+=256) lm = fmaxf(lm, ws[WSG + b*1024 + i]);
  red[tid] = lm; __syncthreads();
  for(int off=128; off; off>>=1){
    if(tid < off) red[tid] = fmaxf(red[tid], red[tid+off]);
    __syncthreads();
  }
  float mx = red[0]; __syncthreads();
  float ls0 = 0.f, ls1 = 0.f;
  for(int i=tid;i<1024;i+=256){
    int fidx = i >> 9, w = i & 511;
    int g = fidx ? g1 : g0;
    float m = emask[b*SS + g*WORDL + w];
    float ev = __expf(ws[WSG + b*1024 + i] - mx)*m;
    es[i] = ev;
    if(fidx) ls1 += ev; else ls0 += ev;
  }
  red[tid] = ls0; __syncthreads();
  for(int off=128; off; off>>=1){ if(tid<off) red[tid]+=red[tid+off]; __syncthreads(); }
  float sum0 = red[0]; __syncthreads();
  red[tid] = ls1; __syncthreads();
  for(int off=128; off; off>>=1){ if(tid<off) red[tid]+=red[tid+off]; __syncthreads(); }
  float sum1 = red[0]; __syncthreads();
  float inv = 1.f/(tf0*sum0 + tf1*sum1);
  for(int s=tid;s<SS;s+=256){
    int sec = s >> 9, w = s & 511;
    float a = 0.f;
    if(sec == g0)      a = tf0*es[w]*inv;
    else if(sec == g1) a = tf1*es[512+w]*inv;
    out[OFF_ATTN + b*SS + s] = a;
    out[OFF_COV  + b*SS + s] = cov[b*SS+s] + a;
  }
}

__global__ void k_ctxp(const float* __restrict__ eo, const float* __restrict__ out,
                       float* __restrict__ ws){
  int blk = blockIdx.x; int b = blk >> 4, ch = blk & 15;
  int d = threadIdx.x;
  int g0 = ((const int*)ws)[WGI + b*2];
  int g1 = ((const int*)ws)[WGI + b*2 + 1];
  float a0 = 0.f, a1 = 0.f;
  #pragma unroll 4
  for(int p = ch*64; p < ch*64 + 64; p++){
    int s = ((p >> 9) ? g1 : g0)*WORDL + (p & 511);
    float a = out[OFF_ATTN + b*SS + s];
    const float* ep = eo + ((size_t)(b*SS + s))*H2;
    a0 = fmaf(a, ep[d],       a0);
    a1 = fmaf(a, ep[d+256],   a1);
  }
  ws[WPART + (size_t)blk*H2 + d]       = a0;
  ws[WPART + (size_t)blk*H2 + d + 256] = a1;
}

__global__ void k_ctx(const float* __restrict__ Wp, const float* __restrict__ bp,
                      float* __restrict__ ws, float* __restrict__ out){
  __shared__ float red[256];
  int b = blockIdx.x, tid = threadIdx.x;
  float c0 = 0.f, c1 = 0.f;
  for(int ch=0; ch<16; ch++){
    c0 += ws[WPART + (size_t)(b*16+ch)*H2 + tid];
    c1 += ws[WPART + (size_t)(b*16+ch)*H2 + tid + 256];
  }
  out[OFF_CTX + b*H2 + tid]       = c0;
  out[OFF_CTX + b*H2 + tid + 256] = c1;
  float hn = out[OFF_H + b*HH + tid];
  float cn = out[OFF_C + b*HH + tid];
  float pv = c0*Wp[tid] + c1*Wp[tid+256] + hn*Wp[512+tid] + cn*Wp[768+tid];
  if(tid < EE) pv = fmaf(ws[WX + b*EE + tid], Wp[1024+tid], pv);
  red[tid] = pv; __syncthreads();
  for(int off=128; off; off>>=1){ if(tid<off) red[tid]+=red[tid+off]; __syncthreads(); }
  if(tid == 0) ws[WPG + b] = sigm(red[0] + bp[0]);
}

// ======== logits v4: LDS outer-product, no cross-lane reduction ========
// Block = 16 vocab rows x 16 batches (256 threads, 1 output each).
// W tile staged in LDS as double-buffered 192-float K-quarters; hb panel
// staged once as hbT[k4][b] (padded). W-row reads broadcast to 16 lanes at
// 4-bank-spaced addresses (conflict-free); hb reads 2-way (free, m136).
#define LROWS 16
#define PADW 49   // 48 float4 + 1 pad
#define PADH 17   // 16 float4 + 1 pad
__global__ void __launch_bounds__(256,2)
k_logits(const float* __restrict__ Wout, const float* __restrict__ bout,
         const float* __restrict__ out, float* __restrict__ ws){
  __shared__ float4 hbT[192*PADH];        // 52.2 KB
  __shared__ float4 Wq[2][LROWS*PADW];    // 25.1 KB
  int tid = threadIdx.x;
  int v0 = blockIdx.x*LROWS;
  // stage hb: thread (b = tid>>4, kcol = tid&15) -> coalesced 256B groups
  {
    int b = tid >> 4, kcol = tid & 15;
    const float* hsrc = out + OFF_H   + b*HH;
    const float* csrc = out + OFF_CTX + b*H2;
    #pragma unroll
    for(int j=0;j<12;j++){
      int k4 = kcol + 16*j;
      float4 v = (k4 < 64) ? *(const float4*)(hsrc + k4*4)
                           : *(const float4*)(csrc + (k4-64)*4);
      hbT[k4*PADH + b] = v;
    }
  }
  // stage W quarter 0
  int r = tid >> 4, cc = tid & 15;
  {
    const float* wr = Wout + (size_t)(v0+r)*KOUT;
    #pragma unroll
    for(int j=0;j<3;j++){
      int k4 = cc + 16*j;
      Wq[0][r*PADW + k4] = *(const float4*)(wr + k4*4);
    }
  }
  __syncthreads();
  int b = tid & 15, vloc = tid >> 4;
  int buf = 0;
  float a0=0,a1=0,a2=0,a3=0;
  #pragma unroll
  for(int q=0;q<4;q++){
    float4 p0,p1,p2;
    if(q<3){
      const float* wr = Wout + (size_t)(v0+r)*KOUT + (q+1)*192;
      p0 = *(const float4*)(wr + cc*4);
      p1 = *(const float4*)(wr + (cc+16)*4);
      p2 = *(const float4*)(wr + (cc+32)*4);
    }
    const float4* wrow = &Wq[buf][vloc*PADW];
    const float4* hcol = &hbT[q*48*PADH + b];
    #pragma unroll
    for(int kk=0;kk<48;kk+=4){
      a0 = dot4(a0, wrow[kk],   hcol[(kk  )*PADH]);
      a1 = dot4(a1, wrow[kk+1], hcol[(kk+1)*PADH]);
      a2 = dot4(a2, wrow[kk+2], hcol[(kk+2)*PADH]);
      a3 = dot4(a3, wrow[kk+3], hcol[(kk+3)*PADH]);
    }
    if(q<3){
      Wq[buf^1][r*PADW + cc]      = p0;
      Wq[buf^1][r*PADW + cc + 16] = p1;
      Wq[buf^1][r*PADW + cc + 32] = p2;
      __syncthreads();
      buf ^= 1;
    }
  }
  float acc = (a0+a1)+(a2+a3);
  int v = v0 + vloc;   // 3125*16 = 50000 exactly, no guard needed
  ws[WLG + (size_t)b*VV + v] = acc + bout[v];
}

// ======== softmax / output kernels ========

__global__ void k_vms(float* __restrict__ ws){
  __shared__ float rm[256], rs[256];
  int blk = blockIdx.x; int b = blk/NCH, ch = blk%NCH;
  int tid = threadIdx.x;
  int v0 = ch*CHSZ; int v1 = v0+CHSZ; if(v1 > VV) v1 = VV;
  float mt = -1e30f, st = 0.f;
  for(int v=v0+tid; v<v1; v+=256){
    float x = ws[WLG + (size_t)b*VV + v];
    if(x > mt){ st = st*__expf(mt - x) + 1.f; mt = x; }
    else       st += __expf(x - mt);
  }
  rm[tid] = mt; rs[tid] = st; __syncthreads();
  for(int off=128; off; off>>=1){
    if(tid < off){
      float ma = rm[tid], mb = rm[tid+off];
      float M = fmaxf(ma, mb);
      rs[tid] = rs[tid]*__expf(ma-M) + rs[tid+off]*__expf(mb-M);
      rm[tid] = M;
    }
    __syncthreads();
  }
  if(tid == 0){ ws[WPM + blk] = rm[0]; ws[WPS + blk] = rs[0]; }
}

__global__ void k_final(const float* __restrict__ zoov, float* __restrict__ ws,
                        float* __restrict__ out){
  int blk = blockIdx.x; int b = blk/NCH, ch = blk%NCH;
  float mx = -1e30f, sm = 0.f;
  for(int i=0;i<NCH;i++){ mx = fmaxf(mx, ws[WPM + b*NCH + i]); }
  for(int i=0;i<NCH;i++){ sm += ws[WPS + b*NCH + i]*__expf(ws[WPM + b*NCH + i] - mx); }
  float scale = ws[WPG + b] / sm;
  int v0 = ch*CHSZ; int v1 = v0+CHSZ; if(v1 > VO) v1 = VO;
  for(int v=v0+threadIdx.x; v<v1; v+=256){
    float r;
    if(v < VV) r = scale*__expf(ws[WLG + (size_t)b*VV + v] - mx);
    else       r = zoov[b*NOOV + v - VV];
    out[OFF_FINAL + (size_t)b*VO + v] = r;
  }
}

__global__ void k_scatter(const int* __restrict__ oov, const float* __restrict__ ws,
                          float* __restrict__ out){
  int blk = blockIdx.x; int b = blk >> 4;
  int s = (blk & 15)*256 + threadIdx.x;
  float a = out[OFF_ATTN + b*SS + s];
  if(a != 0.f){
    float w = (1.f - ws[WPG + b])*a;
    atomicAdd(out + OFF_FINAL + (size_t)b*VO + oov[b*SS + s], w);
  }
}

extern "C" void kernel_launch(void* const* d_in, const int* in_sizes, int n_in,
                              void* d_out, int out_size, void* d_ws, size_t ws_size,
                              hipStream_t stream){
  const int*   inp   = (const int*)  d_in[0];
  const float* h     = (const float*)d_in[1];
  const float* c     = (const float*)d_in[2];
  const float* eo    = (const float*)d_in[3];
  const float* efeat = (const float*)d_in[4];
  const float* eso   = (const float*)d_in[5];
  const float* emask = (const float*)d_in[6];
  const float* smask = (const float*)d_in[7];
  const float* pctx  = (const float*)d_in[8];
  const float* zoov  = (const float*)d_in[9];
  const int*   oov   = (const int*)  d_in[10];
  const float* cov   = (const float*)d_in[11];
  const float* foc   = (const float*)d_in[12];
  const float* emb   = (const float*)d_in[13];
  const float* Wc    = (const float*)d_in[14];
  const float* bc    = (const float*)d_in[15];
  const float* Wih   = (const float*)d_in[16];
  const float* Whh   = (const float*)d_in[17];
  const float* bih   = (const float*)d_in[18];
  const float* bhh   = (const float*)d_in[19];
  const float* Wd    = (const float*)d_in[20];
  const float* bd    = (const float*)d_in[21];
  const float* Wf    = (const float*)d_in[22];
  const float* vsec  = (const float*)d_in[23];
  const float* Wdec  = (const float*)d_in[24];
  const float* bdec  = (const float*)d_in[25];
  const float* wcov  = (const float*)d_in[26];
  const float* vatt  = (const float*)d_in[27];
  const float* Wp    = (const float*)d_in[28];
  const float* bp    = (const float*)d_in[29];
  const float* Wout  = (const float*)d_in[30];
  const float* bout  = (const float*)d_in[31];
  float* out = (float*)d_out;
  float* ws  = (float*)d_ws;

  k_x      <<<64,   256, 0, stream>>>(inp, pctx, emb, Wc, bc, ws);
  k_gates  <<<512,  256, 0, stream>>>(h, c, Wih, Whh, bih, bhh, ws, out);
  k_dd     <<<512,  256, 0, stream>>>(Wd, bd, Wdec, bdec, out, ws);
  k_sec    <<<128,  256, 0, stream>>>(eso, Wf, vsec, ws);
  k_focus  <<<1,     64, 0, stream>>>(inp, smask, foc, ws, out);
  k_score  <<<4096, 256, 0, stream>>>(efeat, cov, wcov, vatt, ws);
  k_af     <<<16,   256, 0, stream>>>(emask, cov, ws, out);
  k_ctxp   <<<256,  256, 0, stream>>>(eo, out, ws);
  k_ctx    <<<16,   256, 0, stream>>>(Wp, bp, ws, out);
  k_logits <<<3125, 256, 0, stream>>>(Wout, bout, out, ws);
  k_vms    <<<208,  256, 0, stream>>>(ws);
  k_final  <<<208,  256, 0, stream>>>(zoov, ws, out);
  k_scatter<<<256,  256, 0, stream>>>(oov, ws, out);
}

// Round 7
// 131.097 us; speedup vs baseline: 2.4913x; 1.1856x over previous
//
#include <hip/hip_runtime.h>
#include <math.h>

// ---------------- problem constants ----------------
#define NB 16
#define SECL 8
#define WORDL 512
#define SS 4096          // SECL*WORDL
#define HH 256           // H
#define EE 128           // E
#define VV 50000
#define NOOV 32
#define VO 50032         // V+NOOV
#define EOS_ID 3
#define H2 512           // 2H
#define KOUT 768         // 3H
#define NCH 13           // vocab chunks
#define CHSZ 4096

// ---------------- d_out offsets (floats) ----------------
#define OFF_FINAL 0
#define OFF_H    800512
#define OFF_C    804608
#define OFF_CTX  808704
#define OFF_ATTN 816896
#define OFF_COV  882432
#define OFF_FOC  947968
#define OFF_SAD  948096

// ---------------- ws offsets (floats) ----------------
#define WX     0         // x: 16*128
#define WD     2048      // d: 16*512
#define WDF    10240     // dfeat: 16*512
#define WSC    18432     // sc: 16*8
#define WGI    18560     // gidx: 32 ints
#define WTF    18592     // topk focus: 32
#define WSG    18624     // score_g: 16*1024
#define WPART  35008     // context partials: 16*16*512
#define WPG    166080    // p_gen: 16
#define WPM    166096    // partial max: 208
#define WPS    166304    // partial sum: 208
#define WLG    166512    // logits: 16*50000

__device__ __forceinline__ float sigm(float x){ return 1.f/(1.f+__expf(-x)); }
__device__ __forceinline__ float tfast(float x){
  float ax = fabsf(x);
  float e  = __expf(-2.f*ax);
  float t  = (1.f-e)/(1.f+e);
  return x < 0.f ? -t : t;
}
__device__ __forceinline__ float dot4(float acc, float4 a, float4 b){
  acc = fmaf(a.x,b.x,acc); acc = fmaf(a.y,b.y,acc);
  acc = fmaf(a.z,b.z,acc); acc = fmaf(a.w,b.w,acc);
  return acc;
}
__device__ __forceinline__ float dot2(float acc, float2 a, float2 b){
  acc = fmaf(a.x,b.x,acc); acc = fmaf(a.y,b.y,acc);
  return acc;
}
__device__ __forceinline__ float mergep(float a, float b, int k, int lane){
  float send = (lane & k) ? a : b;
  float recv = __shfl_xor(send, k);
  return (lane & k) ? b + recv : a + recv;
}
// acc[0..7] -> p where p(lane) = full-wave sum of acc[lane&7]
__device__ __forceinline__ float reduce8(float acc[8], int lane){
  float m0 = mergep(acc[0], acc[1], 1, lane);
  float m1 = mergep(acc[2], acc[3], 1, lane);
  float m2 = mergep(acc[4], acc[5], 1, lane);
  float m3 = mergep(acc[6], acc[7], 1, lane);
  float n0 = mergep(m0, m1, 2, lane);
  float n1 = mergep(m2, m3, 2, lane);
  float p  = mergep(n0, n1, 4, lane);
  p += __shfl_xor(p, 8);
  p += __shfl_xor(p, 16);
  p += __shfl_xor(p, 32);
  return p;
}

// ======== front kernels (R4-proven wave-coalesced matvec skeleton) ========

__global__ void __launch_bounds__(256)
k_x(const int* __restrict__ inp, const float* __restrict__ pc,
    const float* __restrict__ emb, const float* __restrict__ Wc,
    const float* __restrict__ bc, float* __restrict__ ws){
  int lane = threadIdx.x & 63;
  int gw = blockIdx.x*4 + (threadIdx.x >> 6);  // 0..255
  int bg = gw & 1, e = gw >> 1;
  float4 z = {0,0,0,0};
  float4 i0[8], i1[8], i2[8];
  #pragma unroll
  for(int j=0;j<8;j++){
    int b = bg*8 + j;
    i0[j] = *(const float4*)(pc + b*H2 + lane*4);
    i1[j] = *(const float4*)(pc + b*H2 + 256 + lane*4);
    i2[j] = (lane < 32) ? *(const float4*)(emb + (size_t)inp[b]*EE + lane*4) : z;
  }
  const float* wr = Wc + (size_t)e*(H2+EE);
  float4 w0 = *(const float4*)(wr + lane*4);
  float4 w1 = *(const float4*)(wr + 256 + lane*4);
  float4 w2 = (lane < 32) ? *(const float4*)(wr + 512 + lane*4) : z;
  float acc[8];
  #pragma unroll
  for(int j=0;j<8;j++){
    float a = dot4(0.f, w0, i0[j]);
    a = dot4(a, w1, i1[j]);
    a = dot4(a, w2, i2[j]);
    acc[j] = a;
  }
  float p = reduce8(acc, lane);
  if(lane < 8) ws[WX + (bg*8+lane)*EE + e] = p + bc[e];
}

__global__ void __launch_bounds__(256)
k_gates(const float* __restrict__ h, const float* __restrict__ c,
        const float* __restrict__ Wih, const float* __restrict__ Whh,
        const float* __restrict__ bih, const float* __restrict__ bhh,
        const float* __restrict__ ws, float* __restrict__ out){
  __shared__ float g_lds[4][8];
  int lane = threadIdx.x & 63;
  int wv   = threadIdx.x >> 6;
  int j  = blockIdx.x >> 1;
  int bg = blockIdx.x & 1;
  float2 xb[8]; float4 hb[8];
  #pragma unroll
  for(int q=0;q<8;q++){
    int b = bg*8 + q;
    xb[q] = *(const float2*)(ws + WX + b*EE + lane*2);
    hb[q] = *(const float4*)(h + b*HH + lane*4);
  }
  int r = wv*HH + j;
  float2 wx = *(const float2*)(Wih + (size_t)r*EE + lane*2);
  float4 wh = *(const float4*)(Whh + (size_t)r*HH + lane*4);
  float acc[8];
  #pragma unroll
  for(int q=0;q<8;q++)
    acc[q] = dot4(dot2(0.f, wx, xb[q]), wh, hb[q]);
  float p = reduce8(acc, lane);
  if(lane < 8) g_lds[wv][lane] = p + bih[r] + bhh[r];
  __syncthreads();
  if(threadIdx.x < 8){
    int b = bg*8 + threadIdx.x;
    float g0 = g_lds[0][threadIdx.x], g1 = g_lds[1][threadIdx.x];
    float g2 = g_lds[2][threadIdx.x], g3 = g_lds[3][threadIdx.x];
    float cn = sigm(g1)*c[b*HH + j] + sigm(g0)*tfast(g2);
    float hn = sigm(g3)*tfast(cn);
    out[OFF_H + b*HH + j] = hn;
    out[OFF_C + b*HH + j] = cn;
  }
}

__global__ void __launch_bounds__(256)
k_dd(const float* __restrict__ Wd, const float* __restrict__ bd,
     const float* __restrict__ Wdec, const float* __restrict__ bdec,
     const float* __restrict__ out, float* __restrict__ ws){
  int lane = threadIdx.x & 63;
  int gw = blockIdx.x*4 + (threadIdx.x >> 6);  // 0..2047
  int bg = gw & 1, sel = (gw >> 1) & 1, j = gw >> 2;
  float4 d0[8], d1[8];
  #pragma unroll
  for(int q=0;q<8;q++){
    int b = bg*8 + q;
    d0[q] = *(const float4*)(out + OFF_H + b*HH + lane*4);
    d1[q] = *(const float4*)(out + OFF_C + b*HH + lane*4);
  }
  const float* wr = (sel ? Wdec : Wd) + (size_t)j*H2;
  float4 w0 = *(const float4*)(wr + lane*4);
  float4 w1 = *(const float4*)(wr + 256 + lane*4);
  float acc[8];
  #pragma unroll
  for(int q=0;q<8;q++)
    acc[q] = dot4(dot4(0.f, w0, d0[q]), w1, d1[q]);
  float p = reduce8(acc, lane);
  if(lane < 8) ws[(sel ? WDF : WD) + (bg*8+lane)*H2 + j] = p + (sel ? bdec : bd)[j];
}

__global__ void __launch_bounds__(256)
k_sec(const float* __restrict__ eso, const float* __restrict__ Wf,
      const float* __restrict__ vsec, float* __restrict__ ws){
  __shared__ float red[4];
  int lane = threadIdx.x & 63;
  int wv   = threadIdx.x >> 6;
  int bl = blockIdx.x; int b = bl >> 3;
  const float* ep = eso + (size_t)bl*H2;
  float4 es0 = *(const float4*)(ep + lane*4);
  float4 es1 = *(const float4*)(ep + 256 + lane*4);
  const float* dp = ws + WD + b*H2;
  float local = 0.f;
  for(int t=0;t<16;t++){
    int j0 = wv*8 + t*32;
    float acc[8];
    #pragma unroll
    for(int jj=0;jj<8;jj++){
      const float* wr = Wf + (size_t)(j0+jj)*H2;
      float4 w0 = *(const float4*)(wr + lane*4);
      float4 w1 = *(const float4*)(wr + 256 + lane*4);
      acc[jj] = dot4(dot4(0.f, w0, es0), w1, es1);
    }
    float p = reduce8(acc, lane);
    if(lane < 8){
      int j = j0 + lane;
      local += tfast(p + dp[j]) * vsec[j];
    }
  }
  local += __shfl_xor(local, 1);
  local += __shfl_xor(local, 2);
  local += __shfl_xor(local, 4);
  if(lane == 0) red[wv] = local;
  __syncthreads();
  if(threadIdx.x == 0) ws[WSC + bl] = red[0]+red[1]+red[2]+red[3];
}

__global__ void k_focus(const int* __restrict__ inp, const float* __restrict__ smask,
                        const float* __restrict__ focus_in, float* __restrict__ ws,
                        float* __restrict__ out){
  int b = threadIdx.x;
  if(b >= NB) return;
  float sc[SECL], sad[SECL], f[SECL];
  float mx = -1e30f;
  for(int l=0;l<SECL;l++){ sc[l] = ws[WSC + b*SECL + l]; mx = fmaxf(mx, sc[l]); }
  float sum = 0.f;
  for(int l=0;l<SECL;l++){ sad[l] = __expf(sc[l]-mx); sum += sad[l]; }
  float s2 = 0.f;
  for(int l=0;l<SECL;l++){ sad[l] = sad[l]/sum * smask[b*SECL+l]; s2 += sad[l]; }
  for(int l=0;l<SECL;l++){ sad[l] /= s2; out[OFF_SAD + b*SECL + l] = sad[l]; }
  for(int l=0;l<SECL;l++) f[l] = focus_in[b*SECL+l];
  int fi = SECL;
  for(int l=0;l<SECL;l++){ if(f[l] != 0.f){ fi = l; break; } }
  float rem[SECL];
  for(int l=0;l<SECL;l++) rem[l] = (l > fi) ? sad[l] : 0.f;
  float mrb = rem[0]; int mri = 0;
  for(int l=1;l<SECL;l++){ if(rem[l] > mrb){ mrb = rem[l]; mri = l; } }
  float fbm = (fi < SECL) ? sad[fi] : 0.f;
  int cmp = (fbm*2.f > mrb);
  int src = (mrb != 0.f);
  float amb[SECL];
  for(int l=0;l<SECL;l++) amb[l] = (src && l > mri) ? sad[l] : 0.f;
  float am = amb[0]; int ai = 0;
  for(int l=1;l<SECL;l++){ if(amb[l] > am){ am = amb[l]; ai = l; } }
  float fu[SECL]; float fs = 0.f;
  for(int l=0;l<SECL;l++){
    float mrm = (src && l == mri) ? 1.f : 0.f;
    float mam = ((am != 0.f) && l == ai) ? 1.f : 0.f;
    float cf = ((l==fi) ? sad[l] : 0.f) + sad[l]*mrm;
    float cr = sad[l]*(mrm + mam);
    fu[l] = cmp ? cf : cr;
    fs += fu[l];
  }
  float eos = (inp[b] == EOS_ID) ? 1.f : 0.f;
  float fo[SECL];
  for(int l=0;l<SECL;l++){
    fo[l] = eos*(fu[l]/fs) + (1.f-eos)*f[l];
    out[OFF_FOC + b*SECL + l] = fo[l];
  }
  float v1 = fo[0]; int i1 = 0;
  for(int l=1;l<SECL;l++){ if(fo[l] > v1){ v1 = fo[l]; i1 = l; } }
  float v2 = -1e30f; int i2 = 0;
  for(int l=0;l<SECL;l++){ if(l != i1 && fo[l] > v2){ v2 = fo[l]; i2 = l; } }
  ((int*)ws)[WGI + b*2]     = i1;
  ((int*)ws)[WGI + b*2 + 1] = i2;
  ws[WTF + b*2]     = v1;
  ws[WTF + b*2 + 1] = v2;
}

// ======== attention kernels ========

__global__ void k_score(const float* __restrict__ ef, const float* __restrict__ cov,
                        const float* __restrict__ wcov, const float* __restrict__ vatt,
                        float* __restrict__ ws){
  int lane = threadIdx.x & 63;
  int o = blockIdx.x*4 + (threadIdx.x >> 6); // < 16384
  int b = o >> 10, fidx = (o >> 9) & 1, w = o & 511;
  int g = ((const int*)ws)[WGI + b*2 + fidx];
  int s = g*WORDL + w;
  const float* e  = ef + ((size_t)(b*SS + s))*H2;
  const float* df = ws + WDF + b*H2;
  float cv = cov[b*SS + s];
  int j = lane*4;
  float local = 0.f;
  #pragma unroll
  for(int half=0; half<2; half++){
    int jj = j + half*256;
    float4 a  = *(const float4*)(e+jj);
    float4 d4 = *(const float4*)(df+jj);
    float4 wc = *(const float4*)(wcov+jj);
    float4 va = *(const float4*)(vatt+jj);
    local += tfast(a.x + d4.x + cv*wc.x)*va.x;
    local += tfast(a.y + d4.y + cv*wc.y)*va.y;
    local += tfast(a.z + d4.z + cv*wc.z)*va.z;
    local += tfast(a.w + d4.w + cv*wc.w)*va.w;
  }
  for(int off=32; off>0; off>>=1) local += __shfl_xor(local, off);
  if(lane == 0) ws[WSG + o] = local;
}

__global__ void k_af(const float* __restrict__ emask, const float* __restrict__ cov,
                     float* __restrict__ ws, float* __restrict__ out){
  __shared__ float es[1024];
  __shared__ float red[256];
  int b = blockIdx.x, tid = threadIdx.x;
  int g0 = ((int*)ws)[WGI+b*2], g1 = ((int*)ws)[WGI+b*2+1];
  float tf0 = ws[WTF+b*2], tf1 = ws[WTF+b*2+1];
  float lm = -1e30f;
  for(int i=tid;i<1024;i+=256) lm = fmaxf(lm, ws[WSG + b*1024 + i]);
  red[tid] = lm; __syncthreads();
  for(int off=128; off; off>>=1){
    if(tid < off) red[tid] = fmaxf(red[tid], red[tid+off]);
    __syncthreads();
  }
  float mx = red[0]; __syncthreads();
  float ls0 = 0.f, ls1 = 0.f;
  for(int i=tid;i<1024;i+=256){
    int fidx = i >> 9, w = i & 511;
    int g = fidx ? g1 : g0;
    float m = emask[b*SS + g*WORDL + w];
    float ev = __expf(ws[WSG + b*1024 + i] - mx)*m;
    es[i] = ev;
    if(fidx) ls1 += ev; else ls0 += ev;
  }
  red[tid] = ls0; __syncthreads();
  for(int off=128; off; off>>=1){ if(tid<off) red[tid]+=red[tid+off]; __syncthreads(); }
  float sum0 = red[0]; __syncthreads();
  red[tid] = ls1; __syncthreads();
  for(int off=128; off; off>>=1){ if(tid<off) red[tid]+=red[tid+off]; __syncthreads(); }
  float sum1 = red[0]; __syncthreads();
  float inv = 1.f/(tf0*sum0 + tf1*sum1);
  for(int s=tid;s<SS;s+=256){
    int sec = s >> 9, w = s & 511;
    float a = 0.f;
    if(sec == g0)      a = tf0*es[w]*inv;
    else if(sec == g1) a = tf1*es[512+w]*inv;
    out[OFF_ATTN + b*SS + s] = a;
    out[OFF_COV  + b*SS + s] = cov[b*SS+s] + a;
  }
}

__global__ void k_ctxp(const float* __restrict__ eo, const float* __restrict__ out,
                       float* __restrict__ ws){
  int blk = blockIdx.x; int b = blk >> 4, ch = blk & 15;
  int d = threadIdx.x;
  int g0 = ((const int*)ws)[WGI + b*2];
  int g1 = ((const int*)ws)[WGI + b*2 + 1];
  float a0 = 0.f, a1 = 0.f;
  #pragma unroll 4
  for(int p = ch*64; p < ch*64 + 64; p++){
    int s = ((p >> 9) ? g1 : g0)*WORDL + (p & 511);
    float a = out[OFF_ATTN + b*SS + s];
    const float* ep = eo + ((size_t)(b*SS + s))*H2;
    a0 = fmaf(a, ep[d],       a0);
    a1 = fmaf(a, ep[d+256],   a1);
  }
  ws[WPART + (size_t)blk*H2 + d]       = a0;
  ws[WPART + (size_t)blk*H2 + d + 256] = a1;
}

__global__ void k_ctx(const float* __restrict__ Wp, const float* __restrict__ bp,
                      float* __restrict__ ws, float* __restrict__ out){
  __shared__ float red[256];
  int b = blockIdx.x, tid = threadIdx.x;
  float c0 = 0.f, c1 = 0.f;
  for(int ch=0; ch<16; ch++){
    c0 += ws[WPART + (size_t)(b*16+ch)*H2 + tid];
    c1 += ws[WPART + (size_t)(b*16+ch)*H2 + tid + 256];
  }
  out[OFF_CTX + b*H2 + tid]       = c0;
  out[OFF_CTX + b*H2 + tid + 256] = c1;
  float hn = out[OFF_H + b*HH + tid];
  float cn = out[OFF_C + b*HH + tid];
  float pv = c0*Wp[tid] + c1*Wp[tid+256] + hn*Wp[512+tid] + cn*Wp[768+tid];
  if(tid < EE) pv = fmaf(ws[WX + b*EE + tid], Wp[1024+tid], pv);
  red[tid] = pv; __syncthreads();
  for(int off=128; off; off>>=1){ if(tid<off) red[tid]+=red[tid+off]; __syncthreads(); }
  if(tid == 0) ws[WPG + b] = sigm(red[0] + bp[0]);
}

// ======== logits v6: lockstep grid sweep (m13-style contiguous window) ====
// 768 blocks = 3/CU fully resident. At iteration j the whole grid reads the
// contiguous W_out window [j*1536, (j+1)*1536) rows (4.6 MB) -> DRAM-stream
// friendly, unlike v2/v3's ~3000 private scattered 48KB streams.
#define LG_NBLK  768
#define LG_STRIDE (LG_NBLK*2)   // 1536 rows per window
#define LG_ITERS 33             // 33*1536 = 50688 >= 50000
__global__ void __launch_bounds__(256,3)
k_logits(const float* __restrict__ Wout, const float* __restrict__ bout,
         const float* __restrict__ out, float* __restrict__ ws){
  int lane = threadIdx.x & 63;
  int wv   = threadIdx.x >> 6;
  int bg   = wv & 1;             // b-octet
  int rh   = wv >> 1;            // row parity within the block's pair
  float4 hb0[8], hb1[8], hb2[8];
  #pragma unroll
  for(int j=0;j<8;j++){
    int b = bg*8 + j;
    hb0[j] = *(const float4*)(out + OFF_H   + b*HH + lane*4);
    hb1[j] = *(const float4*)(out + OFF_CTX + b*H2 + lane*4);
    hb2[j] = *(const float4*)(out + OFF_CTX + b*H2 + 256 + lane*4);
  }
  int vbase = blockIdx.x*2 + rh;
  // 2-deep prefetch
  const float* p0 = Wout + (size_t)vbase*KOUT + lane*4;
  float4 A0 = *(const float4*)(p0);
  float4 A1 = *(const float4*)(p0+256);
  float4 A2 = *(const float4*)(p0+512);
  int v1c = vbase + LG_STRIDE; if(v1c >= VV) v1c = VV-1;
  const float* p1 = Wout + (size_t)v1c*KOUT + lane*4;
  float4 B0 = *(const float4*)(p1);
  float4 B1 = *(const float4*)(p1+256);
  float4 B2 = *(const float4*)(p1+512);
  for(int j=0;j<LG_ITERS;j++){
    int v = vbase + j*LG_STRIDE;
    float4 C0=B0, C1=B1, C2=B2;
    if(j < LG_ITERS-2){
      int vn = v + 2*LG_STRIDE; if(vn >= VV) vn = VV-1;
      const float* np = Wout + (size_t)vn*KOUT + lane*4;
      C0 = *(const float4*)(np);
      C1 = *(const float4*)(np+256);
      C2 = *(const float4*)(np+512);
    }
    float acc[8];
    #pragma unroll
    for(int q=0;q<8;q++){
      float a = dot4(0.f, A0, hb0[q]);
      a = dot4(a, A1, hb1[q]);
      a = dot4(a, A2, hb2[q]);
      acc[q] = a;
    }
    float p = reduce8(acc, lane);
    if(v < VV && lane < 8)
      ws[WLG + (size_t)(bg*8+lane)*VV + v] = p + bout[v];
    A0=B0; A1=B1; A2=B2;
    B0=C0; B1=C1; B2=C2;
  }
}

// ======== softmax / output kernels ========

__global__ void k_vms(float* __restrict__ ws){
  __shared__ float rm[256], rs[256];
  int blk = blockIdx.x; int b = blk/NCH, ch = blk%NCH;
  int tid = threadIdx.x;
  int v0 = ch*CHSZ; int v1 = v0+CHSZ; if(v1 > VV) v1 = VV;
  float mt = -1e30f, st = 0.f;
  for(int v=v0+tid; v<v1; v+=256){
    float x = ws[WLG + (size_t)b*VV + v];
    if(x > mt){ st = st*__expf(mt - x) + 1.f; mt = x; }
    else       st += __expf(x - mt);
  }
  rm[tid] = mt; rs[tid] = st; __syncthreads();
  for(int off=128; off; off>>=1){
    if(tid < off){
      float ma = rm[tid], mb = rm[tid+off];
      float M = fmaxf(ma, mb);
      rs[tid] = rs[tid]*__expf(ma-M) + rs[tid+off]*__expf(mb-M);
      rm[tid] = M;
    }
    __syncthreads();
  }
  if(tid == 0){ ws[WPM + blk] = rm[0]; ws[WPS + blk] = rs[0]; }
}

__global__ void k_final(const float* __restrict__ zoov, float* __restrict__ ws,
                        float* __restrict__ out){
  int blk = blockIdx.x; int b = blk/NCH, ch = blk%NCH;
  float mx = -1e30f, sm = 0.f;
  for(int i=0;i<NCH;i++){ mx = fmaxf(mx, ws[WPM + b*NCH + i]); }
  for(int i=0;i<NCH;i++){ sm += ws[WPS + b*NCH + i]*__expf(ws[WPM + b*NCH + i] - mx); }
  float scale = ws[WPG + b] / sm;
  int v0 = ch*CHSZ; int v1 = v0+CHSZ; if(v1 > VO) v1 = VO;
  for(int v=v0+threadIdx.x; v<v1; v+=256){
    float r;
    if(v < VV) r = scale*__expf(ws[WLG + (size_t)b*VV + v] - mx);
    else       r = zoov[b*NOOV + v - VV];
    out[OFF_FINAL + (size_t)b*VO + v] = r;
  }
}

__global__ void k_scatter(const int* __restrict__ oov, const float* __restrict__ ws,
                          float* __restrict__ out){
  int blk = blockIdx.x; int b = blk >> 4;
  int s = (blk & 15)*256 + threadIdx.x;
  float a = out[OFF_ATTN + b*SS + s];
  if(a != 0.f){
    float w = (1.f - ws[WPG + b])*a;
    atomicAdd(out + OFF_FINAL + (size_t)b*VO + oov[b*SS + s], w);
  }
}

extern "C" void kernel_launch(void* const* d_in, const int* in_sizes, int n_in,
                              void* d_out, int out_size, void* d_ws, size_t ws_size,
                              hipStream_t stream){
  const int*   inp   = (const int*)  d_in[0];
  const float* h     = (const float*)d_in[1];
  const float* c     = (const float*)d_in[2];
  const float* eo    = (const float*)d_in[3];
  const float* efeat = (const float*)d_in[4];
  const float* eso   = (const float*)d_in[5];
  const float* emask = (const float*)d_in[6];
  const float* smask = (const float*)d_in[7];
  const float* pctx  = (const float*)d_in[8];
  const float* zoov  = (const float*)d_in[9];
  const int*   oov   = (const int*)  d_in[10];
  const float* cov   = (const float*)d_in[11];
  const float* foc   = (const float*)d_in[12];
  const float* emb   = (const float*)d_in[13];
  const float* Wc    = (const float*)d_in[14];
  const float* bc    = (const float*)d_in[15];
  const float* Wih   = (const float*)d_in[16];
  const float* Whh   = (const float*)d_in[17];
  const float* bih   = (const float*)d_in[18];
  const float* bhh   = (const float*)d_in[19];
  const float* Wd    = (const float*)d_in[20];
  const float* bd    = (const float*)d_in[21];
  const float* Wf    = (const float*)d_in[22];
  const float* vsec  = (const float*)d_in[23];
  const float* Wdec  = (const float*)d_in[24];
  const float* bdec  = (const float*)d_in[25];
  const float* wcov  = (const float*)d_in[26];
  const float* vatt  = (const float*)d_in[27];
  const float* Wp    = (const float*)d_in[28];
  const float* bp    = (const float*)d_in[29];
  const float* Wout  = (const float*)d_in[30];
  const float* bout  = (const float*)d_in[31];
  float* out = (float*)d_out;
  float* ws  = (float*)d_ws;

  k_x      <<<64,      256, 0, stream>>>(inp, pctx, emb, Wc, bc, ws);
  k_gates  <<<512,     256, 0, stream>>>(h, c, Wih, Whh, bih, bhh, ws, out);
  k_dd     <<<512,     256, 0, stream>>>(Wd, bd, Wdec, bdec, out, ws);
  k_sec    <<<128,     256, 0, stream>>>(eso, Wf, vsec, ws);
  k_focus  <<<1,        64, 0, stream>>>(inp, smask, foc, ws, out);
  k_score  <<<4096,    256, 0, stream>>>(efeat, cov, wcov, vatt, ws);
  k_af     <<<16,      256, 0, stream>>>(emask, cov, ws, out);
  k_ctxp   <<<256,     256, 0, stream>>>(eo, out, ws);
  k_ctx    <<<16,      256, 0, stream>>>(Wp, bp, ws, out);
  k_logits <<<LG_NBLK, 256, 0, stream>>>(Wout, bout, out, ws);
  k_vms    <<<208,     256, 0, stream>>>(ws);
  k_final  <<<208,     256, 0, stream>>>(zoov, ws, out);
  k_scatter<<<256,     256, 0, stream>>>(oov, ws, out);
}